// Round 20
// baseline (93.131 us; speedup 1.0000x reference)
//
#include <hip/hip_runtime.h>
#include <math.h>

#define BB 128
#define NN 256
#define WW 64
#define DD 128
#define KK 20
#define LL (BB*WW)   // 8192

// ================= Kernel 1: cov partials + xl GEMM + mean/diag — one launch ==============
// blocks [0, 10*split): cov 64x64 upper-tri tiles, acc[4][4] (16 regs, r19-proven)
// blocks [+0, +1024):   xl 32x128 tiles, acc[2][8] (16 regs) + raw att dots (full row in-block)
// blocks [+0, +256):    mean + diag (fp64, r13-proven diagc)
// All paths small-acc: register-safe union (r13's poison was two acc[8][8] GEMMs).
__global__ __launch_bounds__(256) void k_big(const float* __restrict__ data,
                                             const float* __restrict__ linW,
                                             const float* __restrict__ att_i,
                                             const float* __restrict__ att_j,
                                             float* __restrict__ covp,
                                             double* __restrict__ mean,
                                             double* __restrict__ diagc,
                                             float* __restrict__ xl,
                                             float* __restrict__ sil,
                                             float* __restrict__ sjl,
                                             int split, int bpc) {
    __shared__ float S1[128][68];         // 34.8 KB: cov Bs (rows 0..63) / xl Wt
    __shared__ float S2[64][68];          // 17.4 KB: cov As / xl Xs (rows 0..31)
    const int t = threadIdx.x;            // 256 threads
    const int bx = blockIdx.x;
    const int ncov = 10 * split;

    if (bx < ncov) {
        // ---------------- cov path (r19 body, As=S2, Bs=S1) ----------------
        const int tile = bx % 10, bz = bx / 10;
        int rem = tile, bi = 0;
        while (rem >= 4 - bi) { rem -= 4 - bi; ++bi; }
        const int i0 = bi * 64;
        const int j0 = (bi + rem) * 64;
        const int ti = t >> 4, tj = t & 15;

        float acc[4][4] = {};
        const int b0 = bz * bpc;

        #pragma unroll 1
        for (int cb = 0; cb < bpc; ++cb) {
            const int b = b0 + cb;
            #pragma unroll
            for (int e = 0; e < 4; ++e) {
                int idx = t + e * 256, row = idx >> 4, q = idx & 15;
                *(float4*)&S2[row][4 * q] =
                    ((const float4*)(data + ((size_t)b * NN + i0 + row) * WW))[q];
                *(float4*)&S1[row][4 * q] =
                    ((const float4*)(data + ((size_t)b * NN + j0 + row) * WW))[q];
            }
            __syncthreads();

            #pragma unroll 4
            for (int q = 0; q < 16; ++q) {
                float4 wb[4];
                #pragma unroll
                for (int c = 0; c < 4; ++c) wb[c] = *(const float4*)&S1[tj + 16 * c][4 * q];
                #pragma unroll
                for (int r = 0; r < 4; ++r) {
                    float4 xa = *(const float4*)&S2[ti + 16 * r][4 * q];
                    #pragma unroll
                    for (int c = 0; c < 4; ++c)
                        acc[r][c] += xa.x * wb[c].x + xa.y * wb[c].y
                                   + xa.z * wb[c].z + xa.w * wb[c].w;
                }
            }
            __syncthreads();
        }

        #pragma unroll
        for (int r = 0; r < 4; ++r)
            #pragma unroll
            for (int c = 0; c < 4; ++c)
                covp[((size_t)bz * NN + i0 + ti + 16 * r) * NN + j0 + tj + 16 * c] = acc[r][c];
        return;
    }

    if (bx < ncov + 1024) {
        // ---------------- xl path: 32x128 tile, acc[2][8], raw att dots ----------------
        const int r0 = (bx - ncov) * 32;
        const int ti = t >> 4, tj = t & 15;

        #pragma unroll
        for (int e = 0; e < 2; ++e) {
            int idx = t + e * 256, row = idx >> 4, q = idx & 15;
            *(float4*)&S2[row][4 * q] =
                ((const float4*)(data + (size_t)(r0 + row) * WW))[q];
        }
        #pragma unroll
        for (int e = 0; e < 32; ++e) {
            int idx = t + e * 256;        // idx = k*128 + col
            int k = idx >> 7, col = idx & 127;
            S1[col][k] = linW[idx];       // Wt[col][k]
        }
        __syncthreads();

        float acc[2][8] = {};             // rows 2*ti+r, cols tj+16*c
        #pragma unroll
        for (int q = 0; q < 16; ++q) {
            float4 wb[8];
            #pragma unroll
            for (int c = 0; c < 8; ++c) wb[c] = *(const float4*)&S1[tj + 16 * c][4 * q];
            #pragma unroll
            for (int r = 0; r < 2; ++r) {
                float4 xa = *(const float4*)&S2[2 * ti + r][4 * q];
                #pragma unroll
                for (int c = 0; c < 8; ++c)
                    acc[r][c] += xa.x * wb[c].x + xa.y * wb[c].y
                               + xa.z * wb[c].z + xa.w * wb[c].w;
            }
        }
        #pragma unroll
        for (int r = 0; r < 2; ++r)
            #pragma unroll
            for (int c = 0; c < 8; ++c)
                xl[(size_t)(r0 + 2 * ti + r) * DD + tj + 16 * c] = acc[r][c];

        float ai[8], aj[8];
        #pragma unroll
        for (int c = 0; c < 8; ++c) { ai[c] = att_i[tj + 16 * c]; aj[c] = att_j[tj + 16 * c]; }
        #pragma unroll
        for (int r = 0; r < 2; ++r) {
            float pi = 0.f, pj = 0.f;
            #pragma unroll
            for (int c = 0; c < 8; ++c) { pi += acc[r][c] * ai[c]; pj += acc[r][c] * aj[c]; }
            #pragma unroll
            for (int m = 8; m; m >>= 1) { pi += __shfl_xor(pi, m); pj += __shfl_xor(pj, m); }
            if (tj == 0) {
                int v = r0 + 2 * ti + r;
                sil[v] = pi;              // raw; eem added inline in k_attn
                sjl[v] = pj;
            }
        }
        return;
    }

    // ---------------- mean + diag path (fp64) ----------------
    {
        int n = bx - ncov - 1024;
        const int lane = t & 63, wid = t >> 6;
        double s = 0.0, s2 = 0.0;
        for (int c = 0; c < LL / 256; ++c) {
            int l = t + c * 256;
            int b = l >> 6, w = l & 63;
            double v = (double)data[(b * NN + n) * WW + w];
            s += v; s2 += v * v;
        }
        for (int off = 32; off; off >>= 1) {
            s += __shfl_down(s, off);
            s2 += __shfl_down(s2, off);
        }
        __shared__ double redm[4], redq[4];
        if (lane == 0) { redm[wid] = s; redq[wid] = s2; }
        __syncthreads();
        if (t == 0) {
            double S = redm[0] + redm[1] + redm[2] + redm[3];
            double S2s = redq[0] + redq[1] + redq[2] + redq[3];
            double m = S / (double)LL;
            mean[n] = m;
            diagc[n] = S2s - (double)LL * m * m;   // = sum((x-m)^2)
        }
    }
}

// ================= Kernel 2: inline z-reduce (ILP-8) + inline nrm2 + sim + rank top-20 ======
// Fixes r14's 55 us version: 8 accumulators keep 8 loads in flight (r15-proven pattern).
__global__ void k_simtopk(const float* __restrict__ covp,
                          const double* __restrict__ mean,
                          const double* __restrict__ diagc,
                          const float* __restrict__ emb,
                          int* __restrict__ topk, int split) {
    int i = blockIdx.x;
    int t = threadIdx.x;                  // 256 threads
    __shared__ float embI[DD];
    __shared__ double nrmS[NN];
    __shared__ float sim[NN];

    if (t < DD) embI[t] = emb[i * DD + t];

    // covp stored for 64-block pairs (i>>6) <= (j>>6); else read transposed.
    size_t base = ((i >> 6) <= (t >> 6)) ? ((size_t)i * NN + t) : ((size_t)t * NN + i);
    const float* p = covp + base;
    const size_t NS = (size_t)NN * NN;
    double s0 = 0, s1 = 0, s2 = 0, s3 = 0, s4 = 0, s5 = 0, s6 = 0, s7 = 0;
    for (int z = 0; z < split; z += 8) {
        const float* qz = p + (size_t)z * NS;
        s0 += (double)qz[0];
        s1 += (double)qz[NS];
        s2 += (double)qz[2 * NS];
        s3 += (double)qz[3 * NS];
        s4 += (double)qz[4 * NS];
        s5 += (double)qz[5 * NS];
        s6 += (double)qz[6 * NS];
        s7 += (double)qz[7 * NS];
    }
    double s = ((s0 + s1) + (s2 + s3)) + ((s4 + s5) + (s6 + s7));
    s -= (double)LL * mean[i] * mean[t];

    __syncthreads();                      // embI ready

    // dot(emb_i, emb_t) and nrm2_t in one pass (fp64) — r16-proven
    const float4* er = (const float4*)(emb + (size_t)t * DD);
    double dot = 0.0, nt = 0.0;
    #pragma unroll 8
    for (int d4 = 0; d4 < DD / 4; ++d4) {
        float4 v = er[d4];
        dot += (double)embI[4 * d4 + 0] * (double)v.x
             + (double)embI[4 * d4 + 1] * (double)v.y
             + (double)embI[4 * d4 + 2] * (double)v.z
             + (double)embI[4 * d4 + 3] * (double)v.w;
        nt  += (double)v.x * (double)v.x + (double)v.y * (double)v.y
             + (double)v.z * (double)v.z + (double)v.w * (double)v.w;
    }
    nrmS[t] = nt;
    __syncthreads();                      // nrmS ready

    double cosv = dot / (sqrt(nrmS[i]) * sqrt(nt) + 1e-8);
    double stdi = sqrt(diagc[i] + 1e-8);
    double stdj = sqrt(diagc[t] + 1e-8);
    double corrv = s / (stdi * stdj + 1e-8);
    sim[t] = (float)(0.7 * cosv + 0.3 * corrv);
    __syncthreads();

    float my = sim[t];
    int cnt = 0;
    #pragma unroll 8
    for (int u = 0; u < NN; ++u) {
        float sv = sim[u];                // uniform addr -> LDS broadcast
        cnt += (sv > my || (sv == my && u < t)) ? 1 : 0;
    }
    if (cnt < KK) topk[i * KK + cnt] = t;
}

// ================= Kernel 3: fused attention, eem inline (r16-proven body) =================
__global__ __launch_bounds__(512) void k_attn(
        const float* __restrict__ xl, const int* __restrict__ topk,
        const float* __restrict__ sil, const float* __restrict__ sjl,
        const float* __restrict__ att_em_i, const float* __restrict__ att_em_j,
        const float* __restrict__ gnn_bias,
        const float* __restrict__ bn1_g, const float* __restrict__ bn1_b,
        const float* __restrict__ bn2_g, const float* __restrict__ bn2_b,
        const float* __restrict__ emb,
        const float* __restrict__ outW, const float* __restrict__ outb,
        float* __restrict__ out) {
    const int h = blockIdx.x;             // node half: 0 or 1
    const int b = blockIdx.y;             // batch
    const int t = threadIdx.x;            // 512 threads = 8 waves
    const int lane = t & 63, wv = t >> 6;
    const int q = lane & 31, half = lane >> 5;

    __shared__ float xls[NN * DD];        // 128 KB: xl[b]
    __shared__ int2 jwS[128 * KK];        // 20 KB
    __shared__ float eemiS[NN], eemjS[NN];// 2 KB

    {
        const float4* src = (const float4*)(xl + (size_t)b * NN * DD);
        float4* dst = (float4*)xls;
        #pragma unroll
        for (int e = 0; e < 16; ++e) dst[t + e * 512] = src[t + e * 512];
    }

    // inline eem: t<256 -> eemi[node t]; t>=256 -> eemj[node t-256]
    {
        int node = t & 255;
        const float4* erow = (const float4*)(emb + (size_t)node * DD);
        const float4* av = (const float4*)((t < 256) ? att_em_i : att_em_j);
        float d = 0.f;
        #pragma unroll 8
        for (int d4 = 0; d4 < DD / 4; ++d4) {
            float4 e4 = erow[d4];
            float4 a4 = av[d4];
            d += e4.x * a4.x + e4.y * a4.y + e4.z * a4.z + e4.w * a4.w;
        }
        if (t < 256) eemiS[node] = d; else eemjS[node] = d;
    }
    __syncthreads();                      // xls + eem ready

    if (t < 128) {
        int i = h * 128 + t;
        float si = sil[b * NN + i] + eemiS[i];
        int jj[KK]; float aa[KK];
        float amax = -3.4e38f;
        #pragma unroll
        for (int k = 0; k < KK; ++k) {
            int j = topk[i * KK + k];
            jj[k] = j;
            float a = si + sjl[b * NN + j] + eemjS[j];
            a = a > 0.f ? a : 0.2f * a;   // leaky relu
            aa[k] = a;
            amax = fmaxf(amax, a);
        }
        float den = 0.f;
        #pragma unroll
        for (int k = 0; k < KK; ++k) { float e = expf(aa[k] - amax); aa[k] = e; den += e; }
        float r = 1.f / den;
        #pragma unroll
        for (int k = 0; k < KK; ++k)
            jwS[t * KK + k] = make_int2(jj[k], __float_as_int(aa[k] * r));
    }
    __syncthreads();

    const float rbnd = 1.0f / sqrtf(1.0f + 1e-5f);
    const float4 gb = ((const float4*)gnn_bias)[q];
    const float4 g1 = ((const float4*)bn1_g)[q];
    const float4 b1 = ((const float4*)bn1_b)[q];
    const float4 g2 = ((const float4*)bn2_g)[q];
    const float4 b2 = ((const float4*)bn2_b)[q];
    const float4 ow = ((const float4*)outW)[q];
    const float ob0 = outb[0];

    for (int n = 0; n < 8; ++n) {
        int il = wv * 16 + 2 * n + half;  // local node 0..127
        int i  = h * 128 + il;

        float ax = 0.f, ay = 0.f, az = 0.f, aw = 0.f;
        #pragma unroll
        for (int k = 0; k < KK; ++k) {
            int2 p = jwS[il * KK + k];
            float w = __int_as_float(p.y);
            float4 xv = *(const float4*)&xls[p.x * DD + 4 * q];
            ax += w * xv.x; ay += w * xv.y; az += w * xv.z; aw += w * xv.w;
        }

        float4 em = *(const float4*)&emb[(size_t)i * DD + 4 * q];
        float o0 = (ax + gb.x) * rbnd * g1.x + b1.x; o0 = fmaxf(o0, 0.f);
        float o1 = (ay + gb.y) * rbnd * g1.y + b1.y; o1 = fmaxf(o1, 0.f);
        float o2 = (az + gb.z) * rbnd * g1.z + b1.z; o2 = fmaxf(o2, 0.f);
        float o3 = (aw + gb.w) * rbnd * g1.w + b1.w; o3 = fmaxf(o3, 0.f);
        float h0 = o0 * em.x * rbnd * g2.x + b2.x; h0 = fmaxf(h0, 0.f);
        float h1 = o1 * em.y * rbnd * g2.y + b2.y; h1 = fmaxf(h1, 0.f);
        float h2 = o2 * em.z * rbnd * g2.z + b2.z; h2 = fmaxf(h2, 0.f);
        float h3 = o3 * em.w * rbnd * g2.w + b2.w; h3 = fmaxf(h3, 0.f);

        float p4 = h0 * ow.x + h1 * ow.y + h2 * ow.z + h3 * ow.w;
        #pragma unroll
        for (int off = 16; off; off >>= 1) p4 += __shfl_xor(p4, off);
        if (q == 0) out[b * NN + i] = p4 + ob0;
    }
}

extern "C" void kernel_launch(void* const* d_in, const int* in_sizes, int n_in,
                              void* d_out, int out_size, void* d_ws, size_t ws_size,
                              hipStream_t stream) {
    const float* data     = (const float*)d_in[0];
    // d_in[1] = org_edge_index (unused, as in reference)
    const float* emb      = (const float*)d_in[2];
    const float* linW     = (const float*)d_in[3];
    const float* att_i    = (const float*)d_in[4];
    const float* att_j    = (const float*)d_in[5];
    const float* att_em_i = (const float*)d_in[6];
    const float* att_em_j = (const float*)d_in[7];
    const float* gnn_bias = (const float*)d_in[8];
    const float* bn1_g    = (const float*)d_in[9];
    const float* bn1_b    = (const float*)d_in[10];
    const float* bn2_g    = (const float*)d_in[11];
    const float* bn2_b    = (const float*)d_in[12];
    const float* outW     = (const float*)d_in[13];
    const float* outb     = (const float*)d_in[14];
    float* out = (float*)d_out;

    char* ws = (char*)d_ws;
    double* mean   = (double*)(ws + 0);                        // 2 KB
    double* diagc  = (double*)(ws + 2048);                     // 2 KB
    int*    topk   = (int*)(ws + 8192);                        // 20 KB
    float*  sil    = (float*)(ws + (64 << 10));                // 128 KB
    float*  sjl    = (float*)(ws + (192 << 10));               // 128 KB
    float*  covp   = (float*)(ws + (1 << 20));                 // split*256KB (33.5 MB @128)
    float*  xl     = (float*)(ws + (36 << 20));                // 16 MB

    int split = (ws_size >= (size_t)(53 << 20)) ? 128 : 64;
    int bpc = BB / split;

    k_big<<<10 * split + 1024 + NN, 256, 0, stream>>>(
        data, linW, att_i, att_j, covp, mean, diagc, xl, sil, sjl, split, bpc);
    k_simtopk<<<NN, 256, 0, stream>>>(covp, mean, diagc, emb, topk, split);
    dim3 ga(2, BB);
    k_attn<<<ga, 512, 0, stream>>>(xl, topk, sil, sjl, att_em_i, att_em_j, gnn_bias,
                                   bn1_g, bn1_b, bn2_g, bn2_b, emb, outW, outb, out);
}

// Round 21
// 68.632 us; speedup vs baseline: 1.3570x; 1.3570x over previous
//
#include <hip/hip_runtime.h>
#include <math.h>

#define BB 128
#define NN 256
#define WW 64
#define DD 128
#define KK 20
#define LL (BB*WW)   // 8192
#define NPAIR (NN*(NN+1)/2)   // 32896

// ================= Kernel 1: cov partials (64x64 upper-tri tiles) + mean + emb stats ==========
// cov: 10 upper-tri 64x64 tiles x split=128 chunks (bpc=1) -> 1280 blocks = 5/CU uniform.
// acc[4][4] fp32 (16 regs — register-safe union with light pre paths, r12/r19 precedent;
// the r13/r15 poison cases were acc[8][x] unions). reads/FMA = 0.125. 34.8 KB LDS.
__global__ __launch_bounds__(256) void k_covpre(const float* __restrict__ data,
                                                const float* __restrict__ emb,
                                                const float* __restrict__ att_em_i,
                                                const float* __restrict__ att_em_j,
                                                float* __restrict__ covp,
                                                double* __restrict__ mean,
                                                float* __restrict__ eemi,
                                                float* __restrict__ eemj,
                                                double* __restrict__ nrm2,
                                                int split, int bpc) {
    __shared__ float As[64][68];          // 17.4 KB
    __shared__ float Bs[64][68];          // 17.4 KB
    const int t = threadIdx.x;            // 256 threads
    const int bx = blockIdx.x;
    const int ncov = 10 * split;

    if (bx < ncov) {
        // ---------------- cov path ----------------
        const int tile = bx % 10, bz = bx / 10;
        int rem = tile, bi = 0;
        while (rem >= 4 - bi) { rem -= 4 - bi; ++bi; }
        const int i0 = bi * 64;
        const int j0 = (bi + rem) * 64;
        const int ti = t >> 4, tj = t & 15;

        float acc[4][4] = {};
        const int b0 = bz * bpc;

        #pragma unroll 1
        for (int cb = 0; cb < bpc; ++cb) {
            const int b = b0 + cb;
            #pragma unroll
            for (int e = 0; e < 4; ++e) {
                int idx = t + e * 256, row = idx >> 4, q = idx & 15;
                *(float4*)&As[row][4 * q] =
                    ((const float4*)(data + ((size_t)b * NN + i0 + row) * WW))[q];
                *(float4*)&Bs[row][4 * q] =
                    ((const float4*)(data + ((size_t)b * NN + j0 + row) * WW))[q];
            }
            __syncthreads();

            #pragma unroll 4
            for (int q = 0; q < 16; ++q) {
                float4 wb[4];
                #pragma unroll
                for (int c = 0; c < 4; ++c) wb[c] = *(const float4*)&Bs[tj + 16 * c][4 * q];
                #pragma unroll
                for (int r = 0; r < 4; ++r) {
                    float4 xa = *(const float4*)&As[ti + 16 * r][4 * q];
                    #pragma unroll
                    for (int c = 0; c < 4; ++c)
                        acc[r][c] += xa.x * wb[c].x + xa.y * wb[c].y
                                   + xa.z * wb[c].z + xa.w * wb[c].w;
                }
            }
            __syncthreads();
        }

        #pragma unroll
        for (int r = 0; r < 4; ++r)
            #pragma unroll
            for (int c = 0; c < 4; ++c)
                covp[((size_t)bz * NN + i0 + ti + 16 * r) * NN + j0 + tj + 16 * c] = acc[r][c];
        return;
    }

    const int pb = bx - ncov;
    const int lane = t & 63, wid = t >> 6;
    if (pb < NN) {
        // ---------------- mean path (fp64) ----------------
        int n = pb;
        double s = 0.0;
        for (int c = 0; c < LL / 256; ++c) {
            int l = t + c * 256;
            int b = l >> 6, w = l & 63;
            s += (double)data[(b * NN + n) * WW + w];
        }
        for (int off = 32; off; off >>= 1) s += __shfl_down(s, off);
        __shared__ double redm[4];
        if (lane == 0) redm[wid] = s;
        __syncthreads();
        if (t == 0) mean[n] = (redm[0] + redm[1] + redm[2] + redm[3]) / (double)LL;
    } else {
        // ---------------- emb stats path ----------------
        int n = (pb - NN) * 2 + (t >> 7);
        int d = t & 127;
        float e = emb[n * DD + d];
        float pi = e * att_em_i[d];
        float pj = e * att_em_j[d];
        double pn = (double)e * (double)e;
        for (int off = 32; off; off >>= 1) {
            pi += __shfl_down(pi, off);
            pj += __shfl_down(pj, off);
            pn += __shfl_down(pn, off);
        }
        __shared__ float ri[4], rj[4];
        __shared__ double rn[4];
        if (lane == 0) { ri[wid] = pi; rj[wid] = pj; rn[wid] = pn; }
        __syncthreads();
        if ((t & 127) == 0) {
            int w0 = (t >> 7) * 2;
            eemi[n] = ri[w0] + ri[w0 + 1];
            eemj[n] = rj[w0] + rj[w0 + 1];
            nrm2[n] = rn[w0] + rn[w0 + 1];
        }
    }
}

// ================= Kernel 2: xl GEMM + att dots (blocks 0..255)
//                  + covp upper-pair z-reduce ILP-8 -> cov fp64 + mirror (256..384) =========
// Reduce co-resident with GEMM (HBM latency hides under compute — r12/r15 precedent).
__global__ __launch_bounds__(256) void k_phase2(const float* __restrict__ data,
                                                const float* __restrict__ linW,
                                                const float* __restrict__ att_i,
                                                const float* __restrict__ att_j,
                                                const float* __restrict__ eemi,
                                                const float* __restrict__ eemj,
                                                const float* __restrict__ covp,
                                                const double* __restrict__ mean,
                                                double* __restrict__ cov,
                                                float* __restrict__ xl,
                                                float* __restrict__ sil,
                                                float* __restrict__ sjl,
                                                int split) {
    __shared__ float Xs[128][68];
    __shared__ float Wt[DD][68];
    const int t = threadIdx.x;            // 256 threads
    const int bx = blockIdx.x;

    if (bx >= NN) {
        // ---------------- covp z-reduce (upper pairs, ILP-8, mirror) ----------------
        int idx = (bx - NN) * 256 + t;
        if (idx >= NPAIR) return;
        double dn = (double)(2 * NN + 1);
        int i = (int)((dn - sqrt(dn * dn - 8.0 * (double)idx)) * 0.5);
        while ((i + 1) * (2 * NN - i) / 2 <= idx) ++i;
        while (i * (2 * NN - i + 1) / 2 > idx) --i;
        int j = i + (idx - i * (2 * NN - i + 1) / 2);   // i <= j -> covp[z][i][j] valid

        const float* p = covp + (size_t)i * NN + j;
        const size_t NS = (size_t)NN * NN;
        double s0 = 0, s1 = 0, s2 = 0, s3 = 0, s4 = 0, s5 = 0, s6 = 0, s7 = 0;
        for (int z = 0; z < split; z += 8) {
            const float* qz = p + (size_t)z * NS;
            s0 += (double)qz[0];
            s1 += (double)qz[NS];
            s2 += (double)qz[2 * NS];
            s3 += (double)qz[3 * NS];
            s4 += (double)qz[4 * NS];
            s5 += (double)qz[5 * NS];
            s6 += (double)qz[6 * NS];
            s7 += (double)qz[7 * NS];
        }
        double s = ((s0 + s1) + (s2 + s3)) + ((s4 + s5) + (s6 + s7));
        s -= (double)LL * mean[i] * mean[j];
        cov[(size_t)i * NN + j] = s;
        if (i != j) cov[(size_t)j * NN + i] = s;
        return;
    }

    // ---------------- xl + att-dots path (eem folded in, r12 body) ----------------
    const int r0 = bx * 128;
    const int ti = t >> 4, tj = t & 15;

    #pragma unroll
    for (int e = 0; e < 8; ++e) {
        int idx = t + e * 256, row = idx >> 4, q = idx & 15;
        *(float4*)&Xs[row][4 * q] =
            ((const float4*)(data + (size_t)(r0 + row) * WW))[q];
    }
    #pragma unroll
    for (int e = 0; e < 32; ++e) {
        int idx = t + e * 256;            // idx = k*128 + col
        int k = idx >> 7, col = idx & 127;
        Wt[col][k] = linW[idx];
    }
    __syncthreads();

    float acc[8][8] = {};                 // rows 8*ti+r, cols tj+16*c
    #pragma unroll
    for (int q = 0; q < 16; ++q) {
        float4 wb[8];
        #pragma unroll
        for (int c = 0; c < 8; ++c) wb[c] = *(const float4*)&Wt[tj + 16 * c][4 * q];
        #pragma unroll
        for (int r = 0; r < 8; ++r) {
            float4 xa = *(const float4*)&Xs[8 * ti + r][4 * q];
            #pragma unroll
            for (int c = 0; c < 8; ++c)
                acc[r][c] += xa.x * wb[c].x + xa.y * wb[c].y
                           + xa.z * wb[c].z + xa.w * wb[c].w;
        }
    }
    #pragma unroll
    for (int r = 0; r < 8; ++r)
        #pragma unroll
        for (int c = 0; c < 8; ++c)
            xl[(size_t)(r0 + 8 * ti + r) * DD + tj + 16 * c] = acc[r][c];

    float ai[8], aj[8];
    #pragma unroll
    for (int c = 0; c < 8; ++c) { ai[c] = att_i[tj + 16 * c]; aj[c] = att_j[tj + 16 * c]; }
    #pragma unroll
    for (int r = 0; r < 8; ++r) {
        float pi = 0.f, pj = 0.f;
        #pragma unroll
        for (int c = 0; c < 8; ++c) { pi += acc[r][c] * ai[c]; pj += acc[r][c] * aj[c]; }
        #pragma unroll
        for (int m = 8; m; m >>= 1) { pi += __shfl_xor(pi, m); pj += __shfl_xor(pj, m); }
        if (tj == 0) {
            int v = r0 + 8 * ti + r;
            int node = v & (NN - 1);
            sil[v] = pi + eemi[node];
            sjl[v] = pj + eemj[node];
        }
    }
}

// ================= Kernel 3: sim + rank-select top-20 (cov materialized — r15 body) ==========
__global__ void k_simtopk3(const double* __restrict__ cov,
                           const float* __restrict__ emb,
                           const double* __restrict__ nrm2,
                           int* __restrict__ topk) {
    int i = blockIdx.x;
    int t = threadIdx.x;                  // 256 threads
    __shared__ float embI[DD];
    __shared__ float sim[NN];

    if (t < DD) embI[t] = emb[i * DD + t];
    double s = cov[(size_t)i * NN + t];   // single coalesced load
    double stdi = sqrt(cov[(size_t)i * NN + i] + 1e-8);
    double stdj = sqrt(cov[(size_t)t * NN + t] + 1e-8);
    __syncthreads();

    const float4* er = (const float4*)(emb + (size_t)t * DD);
    double dot = 0.0;
    #pragma unroll 8
    for (int d4 = 0; d4 < DD / 4; ++d4) {
        float4 v = er[d4];
        dot += (double)embI[4 * d4 + 0] * (double)v.x
             + (double)embI[4 * d4 + 1] * (double)v.y
             + (double)embI[4 * d4 + 2] * (double)v.z
             + (double)embI[4 * d4 + 3] * (double)v.w;
    }
    double cosv = dot / (sqrt(nrm2[i]) * sqrt(nrm2[t]) + 1e-8);
    double corrv = s / (stdi * stdj + 1e-8);
    sim[t] = (float)(0.7 * cosv + 0.3 * corrv);
    __syncthreads();

    float my = sim[t];
    int cnt = 0;
    #pragma unroll 8
    for (int u = 0; u < NN; ++u) {
        float sv = sim[u];                // uniform addr -> LDS broadcast
        cnt += (sv > my || (sv == my && u < t)) ? 1 : 0;
    }
    if (cnt < KK) topk[i * KK + cnt] = t;
}

// ================= Kernel 4: fused attention (r12 body, eem already in sil/sjl) =============
__global__ __launch_bounds__(512) void k_attn2(
        const float* __restrict__ xl, const int* __restrict__ topk,
        const float* __restrict__ sil, const float* __restrict__ sjl,
        const float* __restrict__ gnn_bias,
        const float* __restrict__ bn1_g, const float* __restrict__ bn1_b,
        const float* __restrict__ bn2_g, const float* __restrict__ bn2_b,
        const float* __restrict__ emb,
        const float* __restrict__ outW, const float* __restrict__ outb,
        float* __restrict__ out) {
    const int h = blockIdx.x;             // node half: 0 or 1
    const int b = blockIdx.y;             // batch
    const int t = threadIdx.x;            // 512 threads = 8 waves
    const int lane = t & 63, wv = t >> 6;
    const int q = lane & 31, half = lane >> 5;

    __shared__ float xls[NN * DD];        // 128 KB: xl[b]
    __shared__ int2 jwS[128 * KK];        // 20 KB

    {
        const float4* src = (const float4*)(xl + (size_t)b * NN * DD);
        float4* dst = (float4*)xls;
        #pragma unroll
        for (int e = 0; e < 16; ++e) dst[t + e * 512] = src[t + e * 512];
    }

    if (t < 128) {
        int i = h * 128 + t;
        float si = sil[b * NN + i];
        int jj[KK]; float aa[KK];
        float amax = -3.4e38f;
        #pragma unroll
        for (int k = 0; k < KK; ++k) {
            int j = topk[i * KK + k];
            jj[k] = j;
            float a = si + sjl[b * NN + j];
            a = a > 0.f ? a : 0.2f * a;   // leaky relu
            aa[k] = a;
            amax = fmaxf(amax, a);
        }
        float den = 0.f;
        #pragma unroll
        for (int k = 0; k < KK; ++k) { float e = expf(aa[k] - amax); aa[k] = e; den += e; }
        float r = 1.f / den;
        #pragma unroll
        for (int k = 0; k < KK; ++k)
            jwS[t * KK + k] = make_int2(jj[k], __float_as_int(aa[k] * r));
    }
    __syncthreads();

    const float rbnd = 1.0f / sqrtf(1.0f + 1e-5f);
    const float4 gb = ((const float4*)gnn_bias)[q];
    const float4 g1 = ((const float4*)bn1_g)[q];
    const float4 b1 = ((const float4*)bn1_b)[q];
    const float4 g2 = ((const float4*)bn2_g)[q];
    const float4 b2 = ((const float4*)bn2_b)[q];
    const float4 ow = ((const float4*)outW)[q];
    const float ob0 = outb[0];

    for (int n = 0; n < 8; ++n) {
        int il = wv * 16 + 2 * n + half;  // local node 0..127
        int i  = h * 128 + il;

        float ax = 0.f, ay = 0.f, az = 0.f, aw = 0.f;
        #pragma unroll
        for (int k = 0; k < KK; ++k) {
            int2 p = jwS[il * KK + k];
            float w = __int_as_float(p.y);
            float4 xv = *(const float4*)&xls[p.x * DD + 4 * q];
            ax += w * xv.x; ay += w * xv.y; az += w * xv.z; aw += w * xv.w;
        }

        float4 em = *(const float4*)&emb[(size_t)i * DD + 4 * q];
        float o0 = (ax + gb.x) * rbnd * g1.x + b1.x; o0 = fmaxf(o0, 0.f);
        float o1 = (ay + gb.y) * rbnd * g1.y + b1.y; o1 = fmaxf(o1, 0.f);
        float o2 = (az + gb.z) * rbnd * g1.z + b1.z; o2 = fmaxf(o2, 0.f);
        float o3 = (aw + gb.w) * rbnd * g1.w + b1.w; o3 = fmaxf(o3, 0.f);
        float h0 = o0 * em.x * rbnd * g2.x + b2.x; h0 = fmaxf(h0, 0.f);
        float h1 = o1 * em.y * rbnd * g2.y + b2.y; h1 = fmaxf(h1, 0.f);
        float h2 = o2 * em.z * rbnd * g2.z + b2.z; h2 = fmaxf(h2, 0.f);
        float h3 = o3 * em.w * rbnd * g2.w + b2.w; h3 = fmaxf(h3, 0.f);

        float p4 = h0 * ow.x + h1 * ow.y + h2 * ow.z + h3 * ow.w;
        #pragma unroll
        for (int off = 16; off; off >>= 1) p4 += __shfl_xor(p4, off);
        if (q == 0) out[b * NN + i] = p4 + ob0;
    }
}

extern "C" void kernel_launch(void* const* d_in, const int* in_sizes, int n_in,
                              void* d_out, int out_size, void* d_ws, size_t ws_size,
                              hipStream_t stream) {
    const float* data     = (const float*)d_in[0];
    // d_in[1] = org_edge_index (unused, as in reference)
    const float* emb      = (const float*)d_in[2];
    const float* linW     = (const float*)d_in[3];
    const float* att_i    = (const float*)d_in[4];
    const float* att_j    = (const float*)d_in[5];
    const float* att_em_i = (const float*)d_in[6];
    const float* att_em_j = (const float*)d_in[7];
    const float* gnn_bias = (const float*)d_in[8];
    const float* bn1_g    = (const float*)d_in[9];
    const float* bn1_b    = (const float*)d_in[10];
    const float* bn2_g    = (const float*)d_in[11];
    const float* bn2_b    = (const float*)d_in[12];
    const float* outW     = (const float*)d_in[13];
    const float* outb     = (const float*)d_in[14];
    float* out = (float*)d_out;

    char* ws = (char*)d_ws;
    double* mean   = (double*)(ws + 0);                        // 2 KB
    double* nrm2   = (double*)(ws + 2048);                     // 2 KB
    float*  eemi   = (float*)(ws + 4096);                      // 1 KB
    float*  eemj   = (float*)(ws + 5120);                      // 1 KB
    int*    topk   = (int*)(ws + 8192);                        // 20 KB
    float*  sil    = (float*)(ws + (64 << 10));                // 128 KB
    float*  sjl    = (float*)(ws + (192 << 10));               // 128 KB
    double* cov    = (double*)(ws + (320 << 10));              // 512 KB
    float*  covp   = (float*)(ws + (1 << 20));                 // split*256KB (33.5 MB @128)
    float*  xl     = (float*)(ws + (36 << 20));                // 16 MB

    int split = (ws_size >= (size_t)(53 << 20)) ? 128 : 64;
    int bpc = BB / split;

    k_covpre<<<10 * split + NN + NN / 2, 256, 0, stream>>>(
        data, emb, att_em_i, att_em_j, covp, mean, eemi, eemj, nrm2, split, bpc);
    k_phase2<<<NN + (NPAIR + 255) / 256, 256, 0, stream>>>(
        data, linW, att_i, att_j, eemi, eemj, covp, mean, cov, xl, sil, sjl, split);
    k_simtopk3<<<NN, 256, 0, stream>>>(cov, emb, nrm2, topk);
    dim3 ga(2, BB);
    k_attn2<<<ga, 512, 0, stream>>>(xl, topk, sil, sjl, gnn_bias,
                                    bn1_g, bn1_b, bn2_g, bn2_b, emb, outW, outb, out);
}